// Round 3
// baseline (510.997 us; speedup 1.0000x reference)
//
#include <hip/hip_runtime.h>
#include <math.h>

#define KGT   16
#define NCAND 9
#define NLVL  5
#define NPRI  8525
#define NCLS  80
#define NIMG  32

#define SCAN_BLOCKS  640                 // 2560 waves: one per (image,gt,level)
#define FOCAL_BLOCKS 1408
#define TOTAL_BLOCKS 2048                // exactly resident at 8 blocks/CU
#define NELEM (NIMG * NPRI * NCLS)       // 21,824,000
#define N4    (NELEM / 4)                // 5,456,000

// ws: [0..15] float acc (acc[0]=focal base sum), ((int*)ws)[8]=done counter,
//     [64..]  float povs[2560*9], then int idxs[2560*9]

__device__ __forceinline__ float focal_elem(float x)
{
    float e  = __expf(-fabsf(x));                 // e^{-|x|}
    float t  = 1.f + e;
    float r  = __builtin_amdgcn_rcpf(t);          // ~1ulp rcp, no IEEE-div fixup
    float sp = fmaxf(x, 0.f) + __logf(t);         // softplus(x)
    float nm = (x >= 0.f) ? 1.f : e;
    float p  = nm * r;                            // sigmoid(x)
    return p * p * sp;
}

__device__ __forceinline__ float focal4(float4 v)
{
    return focal_elem(v.x) + focal_elem(v.y) + focal_elem(v.z) + focal_elem(v.w);
}

__global__ __launch_bounds__(256)
void atss_fused(const float* __restrict__ locs,
                const float* __restrict__ scores,
                const float* __restrict__ boxes,
                const int*   __restrict__ labels,
                const float* __restrict__ priors,
                float* __restrict__ acc,
                float* __restrict__ povs,
                int*   __restrict__ idxs,
                int*   __restrict__ done,
                float* __restrict__ out)
{
    const int tid = threadIdx.x;
    const int blk = blockIdx.x;
    const int SPLc[6] = {0, 6400, 8000, 8400, 8500, 8525};

    __shared__ float wsum[4];
    __shared__ int   sflag;
    // decide-phase LDS (allocated always; ~12.5 KB)
    __shared__ float sb[NIMG * KGT][4];
    __shared__ int   sl[NIMG * KGT];
    __shared__ float thrs[NIMG * KGT];
    __shared__ float red_corr, red_loc;
    __shared__ int   red_cnt;

    if (blk < SCAN_BLOCKS) {
        // ------------- top-9 scan: one wave per task t = (b, g, l)
        const int lane = tid & 63;
        const int t = blk * 4 + (tid >> 6);
        const int b = t / (KGT * NLVL);
        const int r = t % (KGT * NLVL);
        const int g = r / NLVL;
        const int l = r % NLVL;
        const int base = SPLc[l];
        const int Pl   = SPLc[l + 1] - base;

        float4 bx = ((const float4*)boxes)[b * KGT + g];
        const float gcx = (bx.x + bx.z) * 0.5f;
        const float gcy = (bx.y + bx.w) * 0.5f;

        unsigned long long L[NCAND];
        #pragma unroll
        for (int s = 0; s < NCAND; ++s) L[s] = ~0ull;

        for (int i = lane; i < Pl; i += 64) {
            float2 pc = ((const float2*)priors)[(base + i) * 2];
            float dx = gcx - pc.x, dy = gcy - pc.y;
            float dist = sqrtf(dx * dx + dy * dy);     // exact: match ref rounding
            unsigned long long pk =
                ((unsigned long long)__float_as_uint(dist) << 32) | (unsigned)i;
            if (pk < L[NCAND - 1]) {
                L[NCAND - 1] = pk;
                #pragma unroll
                for (int s = NCAND - 1; s >= 1; --s) {
                    if (L[s] < L[s - 1]) {
                        unsigned long long tw = L[s]; L[s] = L[s - 1]; L[s - 1] = tw;
                    } else break;
                }
            }
        }
        // 9 rounds of wave-wide min extraction (packed keys unique)
        unsigned long long mine = 0;
        #pragma unroll
        for (int rnd = 0; rnd < NCAND; ++rnd) {
            unsigned long long m = L[0];
            #pragma unroll
            for (int off = 1; off < 64; off <<= 1) {
                unsigned long long o = __shfl_xor(m, off);
                m = (o < m) ? o : m;
            }
            if (L[0] == m) {
                #pragma unroll
                for (int s = 0; s < NCAND - 1; ++s) L[s] = L[s + 1];
                L[NCAND - 1] = ~0ull;
            }
            if (lane == rnd) mine = m;
        }
        if (lane < NCAND) {
            int idx = (int)(unsigned)(mine & 0xffffffffull);
            float4 pr = ((const float4*)priors)[base + idx];
            float px0 = pr.x - pr.z * 0.5f, py0 = pr.y - pr.w * 0.5f;
            float px1 = pr.x + pr.z * 0.5f, py1 = pr.y + pr.w * 0.5f;
            float iw = fmaxf(fminf(bx.z, px1) - fmaxf(bx.x, px0), 0.f);
            float ih = fmaxf(fminf(bx.w, py1) - fmaxf(bx.y, py0), 0.f);
            float inter = iw * ih;
            float areaA = (bx.z - bx.x) * (bx.w - bx.y);
            float areaP = (px1 - px0) * (py1 - py0);
            int o = t * NCAND + lane;
            povs[o] = inter / (areaA + areaP - inter);
            idxs[o] = idx;
        }
    } else {
        // ------------- focal base: 0.75 * sum p^2 * softplus(x), 4-deep ILP
        const float4* s4 = (const float4*)scores;
        const int S = FOCAL_BLOCKS * 256;
        int gid = (blk - SCAN_BLOCKS) * 256 + tid;
        float lsum = 0.f;
        for (int bse = gid; bse < N4; bse += 4 * S) {
            int i1 = bse + S, i2 = bse + 2 * S, i3 = bse + 3 * S;
            float4 v0 = s4[bse];
            float4 v1 = s4[min(i1, N4 - 1)];
            float4 v2 = s4[min(i2, N4 - 1)];
            float4 v3 = s4[min(i3, N4 - 1)];
            float t0 = focal4(v0);
            float t1 = focal4(v1);
            float t2 = focal4(v2);
            float t3 = focal4(v3);
            lsum += t0;
            lsum += (i1 < N4) ? t1 : 0.f;
            lsum += (i2 < N4) ? t2 : 0.f;
            lsum += (i3 < N4) ? t3 : 0.f;
        }
        #pragma unroll
        for (int off = 32; off > 0; off >>= 1) lsum += __shfl_down(lsum, off);
        if ((tid & 63) == 0) wsum[tid >> 6] = lsum;
        __syncthreads();
        if (tid == 0)
            atomicAdd(&acc[0], 0.75f * (wsum[0] + wsum[1] + wsum[2] + wsum[3]));
    }

    // ------------- completion protocol: last block runs decide + finalize
    __threadfence();
    __syncthreads();
    if (tid == 0) sflag = atomicAdd(done, 1);
    __syncthreads();
    if (sflag != TOTAL_BLOCKS - 1) return;
    __threadfence();   // acquire: see all blocks' povs/idxs/acc writes

    if (tid == 0) { red_corr = 0.f; red_loc = 0.f; red_cnt = 0; }
    for (int e = tid; e < NIMG * KGT; e += 256) {
        float4 bxv = ((const float4*)boxes)[e];
        sb[e][0] = bxv.x; sb[e][1] = bxv.y; sb[e][2] = bxv.z; sb[e][3] = bxv.w;
        sl[e] = labels[e];
    }
    __syncthreads();

    // adaptive thresholds: mean + std(ddof=1) over each (b,g)'s 45 IoUs
    for (int e = tid; e < NIMG * KGT; e += 256) {
        const float* pv = povs + e * 45;
        float s = 0.f;
        for (int q = 0; q < 45; ++q) s += pv[q];
        float mean = s / 45.f;
        float ss = 0.f;
        for (int q = 0; q < 45; ++q) { float d = pv[q] - mean; ss += d * d; }
        thrs[e] = mean + sqrtf(ss / 44.f);
    }
    __syncthreads();

    // per (image, level, cand): argmax over GTs, focal correction + CIoU
    for (int e = tid; e < NIMG * NLVL * NCAND; e += 256) {
        int b = e / (NLVL * NCAND);
        int q = e % (NLVL * NCAND);
        int l = q / NCAND, j = q % NCAND;
        float bestv = -1.f; int bestg = 0;
        for (int gg = 0; gg < KGT; ++gg) {
            int bg = b * KGT + gg;
            float m = povs[bg * 45 + q];
            int  pi = idxs[bg * 45 + q];
            float4 pr = ((const float4*)priors)[SPLc[l] + pi];
            bool inside = (sb[bg][0] < pr.x) && (pr.x < sb[bg][2]) &&
                          (sb[bg][1] < pr.y) && (pr.y < sb[bg][3]);
            float mm = ((m > thrs[bg]) && inside) ? m : 0.f;
            if (mm > bestv) { bestv = mm; bestg = gg; }   // first max wins
        }
        if (bestv > 0.f) {
            int bg = b * KGT + bestg;
            int lab = sl[bg];
            long pos = (long)b * NPRI + SPLc[l] + j;      // ref's .at[arange(9)] quirk
            float x  = scores[pos * NCLS + (lab - 1)];
            float ee = expf(-fabsf(x));
            float l1 = log1pf(ee);
            float spp = fmaxf(x, 0.f) + l1;
            float spn = fmaxf(-x, 0.f) + l1;
            float p   = (x >= 0.f) ? 1.f / (1.f + ee) : ee / (1.f + ee);
            float corr = 0.25f * (1.f - p) * (1.f - p) * spn - 0.75f * p * p * spp;

            int pi = idxs[bg * 45 + q];
            float4 pr = ((const float4*)priors)[SPLc[l] + pi];
            float4 lc = ((const float4*)locs)[b * NPRI + SPLc[l] + pi];
            float cx = lc.x * pr.z / 10.f + pr.x;
            float cy = lc.y * pr.w / 10.f + pr.y;
            float w  = expf(lc.z / 5.f) * pr.z;
            float h  = expf(lc.w / 5.f) * pr.w;
            float qx0 = cx - w * 0.5f, qy0 = cy - h * 0.5f;
            float qx1 = cx + w * 0.5f, qy1 = cy + h * 0.5f;
            float gx0 = sb[bg][0], gy0 = sb[bg][1], gx1 = sb[bg][2], gy1 = sb[bg][3];
            float w1 = qx1 - qx0, h1 = qy1 - qy0, w2 = gx1 - gx0, h2 = gy1 - gy0;
            float iw = fmaxf(fminf(qx1, gx1) - fmaxf(qx0, gx0), 0.f);
            float ih = fmaxf(fminf(qy1, gy1) - fmaxf(qy0, gy0), 0.f);
            float inter = iw * ih;
            float iou = inter / (w1 * h1 + w2 * h2 - inter);
            float dcx = (qx0 + qx1) * 0.5f - (gx0 + gx1) * 0.5f;
            float dcy = (qy0 + qy1) * 0.5f - (gy0 + gy1) * 0.5f;
            float rho2 = dcx * dcx + dcy * dcy;
            float ex = fmaxf(qx1, gx1) - fminf(qx0, gx0);
            float ey = fmaxf(qy1, gy1) - fminf(qy0, gy0);
            float cdiag = ex * ex + ey * ey;
            float da = atanf(w2 / h2) - atanf(w1 / h1);
            float v  = 0.4052847345693511f * da * da;     // 4/pi^2
            float alpha = v / (1.f - iou + v);
            float ci = iou - rho2 / cdiag - alpha * v;
            ci = fminf(fmaxf(ci, -1.f), 1.f);

            atomicAdd(&red_corr, corr);
            atomicAdd(&red_loc, 1.f - ci);
            atomicAdd(&red_cnt, 1);
        }
    }
    __syncthreads();
    if (tid == 0) {
        float cnt = (float)red_cnt;
        float conf = (acc[0] + red_corr) / cnt;        // ref: / n_pos (no clamp)
        float loc  = red_loc / fmaxf(cnt, 1.f);        // ref: clamped denom
        out[0] = conf + loc;
    }
}

extern "C" void kernel_launch(void* const* d_in, const int* in_sizes, int n_in,
                              void* d_out, int out_size, void* d_ws, size_t ws_size,
                              hipStream_t stream)
{
    const float* locs   = (const float*)d_in[0];   // (32, 8525, 4)
    const float* scores = (const float*)d_in[1];   // (32, 8525, 80)
    const float* boxes  = (const float*)d_in[2];   // (32, 16, 4)
    const int*   labels = (const int*)d_in[3];     // (32, 16)
    const float* priors = (const float*)d_in[4];   // (8525, 4)
    float* out = (float*)d_out;

    float* acc  = (float*)d_ws;
    int*   done = (int*)d_ws + 8;
    float* povs = (float*)((char*)d_ws + 64);
    int*   idxs = (int*)((char*)d_ws + 64 + NIMG * KGT * NLVL * NCAND * sizeof(float));

    hipMemsetAsync(d_ws, 0, 64, stream);
    atss_fused<<<TOTAL_BLOCKS, 256, 0, stream>>>(locs, scores, boxes, labels,
                                                 priors, acc, povs, idxs, done, out);
}

// Round 4
// 191.326 us; speedup vs baseline: 2.6708x; 2.6708x over previous
//
#include <hip/hip_runtime.h>
#include <math.h>

#define KGT   16
#define NCAND 9
#define NLVL  5
#define NPRI  8525
#define NCLS  80
#define NIMG  32

#define SCAN_BLOCKS  640                 // 2560 waves: one per (image,gt,level)
#define FOCAL_BLOCKS 1408
#define TOTAL_BLOCKS 2048                // exactly resident at 8 blocks/CU
#define NELEM (NIMG * NPRI * NCLS)       // 21,824,000
#define N4    (NELEM / 4)                // 5,456,000
#define NTASK (NIMG * KGT * NLVL)        // 2560

// ws layout (bytes), all regions fully written each call (no init needed):
//   povs     @ 0          : 23040 f32  (92160 B)
//   idxs     @ 92160      : 23040 i32  (92160 B)
//   partials @ 184320     : 1408  f32  (per-focal-block partial sums)
//   imgstats @ 192000     : 32 × {corr, loc, cnt} f32 (96 floats)
#define OFF_IDXS  92160
#define OFF_PART  184320
#define OFF_IMG   192000

__device__ __forceinline__ float focal_elem(float x)
{
    float e  = __expf(-fabsf(x));                 // e^{-|x|}
    float t  = 1.f + e;
    float r  = __builtin_amdgcn_rcpf(t);          // ~1ulp rcp, no IEEE-div fixup
    float sp = fmaxf(x, 0.f) + __logf(t);         // softplus(x)
    float nm = (x >= 0.f) ? 1.f : e;
    float p  = nm * r;                            // sigmoid(x)
    return p * p * sp;
}

__device__ __forceinline__ float focal4(float4 v)
{
    return focal_elem(v.x) + focal_elem(v.y) + focal_elem(v.z) + focal_elem(v.w);
}

// ------------------------------------------------------------------ kernel 1
__global__ __launch_bounds__(256)
void atss_main(const float* __restrict__ scores,
               const float* __restrict__ boxes,
               const float* __restrict__ priors,
               float* __restrict__ povs,
               int*   __restrict__ idxs,
               float* __restrict__ partials)
{
    const int tid = threadIdx.x;
    const int blk = blockIdx.x;
    const int SPLc[6] = {0, 6400, 8000, 8400, 8500, 8525};
    __shared__ float wsum[4];

    if (blk < SCAN_BLOCKS) {
        // one wave per task t = (b, g, l): top-9 nearest priors + IoU
        const int lane = tid & 63;
        const int t = blk * 4 + (tid >> 6);
        const int b = t / (KGT * NLVL);
        const int r = t % (KGT * NLVL);
        const int g = r / NLVL;
        const int l = r % NLVL;
        const int base = SPLc[l];
        const int Pl   = SPLc[l + 1] - base;

        float4 bx = ((const float4*)boxes)[b * KGT + g];
        const float gcx = (bx.x + bx.z) * 0.5f;
        const float gcy = (bx.y + bx.w) * 0.5f;

        unsigned long long L[NCAND];
        #pragma unroll
        for (int s = 0; s < NCAND; ++s) L[s] = ~0ull;

        for (int i = lane; i < Pl; i += 64) {
            float2 pc = ((const float2*)priors)[(base + i) * 2];
            float dx = gcx - pc.x, dy = gcy - pc.y;
            float dist = sqrtf(dx * dx + dy * dy);     // exact, matches ref rounding
            unsigned long long pk =
                ((unsigned long long)__float_as_uint(dist) << 32) | (unsigned)i;
            if (pk < L[NCAND - 1]) {                   // lexicographic (dist, idx)
                L[NCAND - 1] = pk;
                #pragma unroll
                for (int s = NCAND - 1; s >= 1; --s) {
                    if (L[s] < L[s - 1]) {
                        unsigned long long tw = L[s]; L[s] = L[s - 1]; L[s - 1] = tw;
                    } else break;
                }
            }
        }
        // 9 rounds of wave-wide min extraction (packed keys unique)
        unsigned long long mine = 0;
        #pragma unroll
        for (int rnd = 0; rnd < NCAND; ++rnd) {
            unsigned long long m = L[0];
            #pragma unroll
            for (int off = 1; off < 64; off <<= 1) {
                unsigned long long o = __shfl_xor(m, off);
                m = (o < m) ? o : m;
            }
            if (L[0] == m) {
                #pragma unroll
                for (int s = 0; s < NCAND - 1; ++s) L[s] = L[s + 1];
                L[NCAND - 1] = ~0ull;
            }
            if (lane == rnd) mine = m;
        }
        if (lane < NCAND) {
            int idx = (int)(unsigned)(mine & 0xffffffffull);
            float4 pr = ((const float4*)priors)[base + idx];
            float px0 = pr.x - pr.z * 0.5f, py0 = pr.y - pr.w * 0.5f;
            float px1 = pr.x + pr.z * 0.5f, py1 = pr.y + pr.w * 0.5f;
            float iw = fmaxf(fminf(bx.z, px1) - fmaxf(bx.x, px0), 0.f);
            float ih = fmaxf(fminf(bx.w, py1) - fmaxf(bx.y, py0), 0.f);
            float inter = iw * ih;
            float areaA = (bx.z - bx.x) * (bx.w - bx.y);
            float areaP = (px1 - px0) * (py1 - py0);
            int o = t * NCAND + lane;
            povs[o] = inter / (areaA + areaP - inter);
            idxs[o] = idx;
        }
        return;
    }

    // focal base: sum p^2 * softplus(x) over every logit, 4 loads in flight
    const float4* s4 = (const float4*)scores;
    const int S = FOCAL_BLOCKS * 256;
    int gid = (blk - SCAN_BLOCKS) * 256 + tid;
    float lsum = 0.f;
    for (int bse = gid; bse < N4; bse += 4 * S) {
        int i1 = bse + S, i2 = bse + 2 * S, i3 = bse + 3 * S;
        float4 v0 = s4[bse];
        float4 v1 = s4[min(i1, N4 - 1)];
        float4 v2 = s4[min(i2, N4 - 1)];
        float4 v3 = s4[min(i3, N4 - 1)];
        float t0 = focal4(v0);
        float t1 = focal4(v1);
        float t2 = focal4(v2);
        float t3 = focal4(v3);
        lsum += t0;
        lsum += (i1 < N4) ? t1 : 0.f;
        lsum += (i2 < N4) ? t2 : 0.f;
        lsum += (i3 < N4) ? t3 : 0.f;
    }
    #pragma unroll
    for (int off = 32; off > 0; off >>= 1) lsum += __shfl_down(lsum, off);
    if ((tid & 63) == 0) wsum[tid >> 6] = lsum;
    __syncthreads();
    if (tid == 0)
        partials[blk - SCAN_BLOCKS] = wsum[0] + wsum[1] + wsum[2] + wsum[3];
}

// ------------------------------------------------------------------ kernel 2
// one block per image: threshold, argmax-over-GT, focal correction + CIoU
__global__ __launch_bounds__(256)
void atss_decide(const float* __restrict__ locs,
                 const float* __restrict__ scores,
                 const float* __restrict__ boxes,
                 const int*   __restrict__ labels,
                 const float* __restrict__ priors,
                 const float* __restrict__ povs,
                 const int*   __restrict__ idxs,
                 float* __restrict__ imgstats)
{
    const int tid = threadIdx.x;
    const int b = blockIdx.x;
    const int SPLc[6] = {0, 6400, 8000, 8400, 8500, 8525};

    __shared__ float pov[KGT * 45];
    __shared__ int   tix[KGT * 45];
    __shared__ float sbox[KGT][4];
    __shared__ int   slab[KGT];
    __shared__ float thr[KGT];
    __shared__ float rc, rl;
    __shared__ int   rn;

    if (tid == 0) { rc = 0.f; rl = 0.f; rn = 0; }
    for (int e = tid; e < KGT * 45; e += 256) {
        pov[e] = povs[b * (KGT * 45) + e];
        tix[e] = idxs[b * (KGT * 45) + e];
    }
    if (tid < KGT) {
        float4 bxv = ((const float4*)boxes)[b * KGT + tid];
        sbox[tid][0] = bxv.x; sbox[tid][1] = bxv.y;
        sbox[tid][2] = bxv.z; sbox[tid][3] = bxv.w;
        slab[tid] = labels[b * KGT + tid];
    }
    __syncthreads();

    if (tid < KGT) {   // mean + std(ddof=1) over the 45 candidate IoUs
        float s = 0.f;
        for (int q = 0; q < 45; ++q) s += pov[tid * 45 + q];
        float mean = s / 45.f;
        float ss = 0.f;
        for (int q = 0; q < 45; ++q) { float d = pov[tid * 45 + q] - mean; ss += d * d; }
        thr[tid] = mean + sqrtf(ss / 44.f);
    }
    __syncthreads();

    if (tid < NLVL * NCAND) {
        int l = tid / NCAND, j = tid % NCAND;
        float bestv = -1.f; int bestg = 0;
        #pragma unroll
        for (int gg = 0; gg < KGT; ++gg) {
            float m = pov[gg * 45 + tid];
            int pi = tix[gg * 45 + tid];
            float4 pr = ((const float4*)priors)[SPLc[l] + pi];
            bool inside = (sbox[gg][0] < pr.x) && (pr.x < sbox[gg][2]) &&
                          (sbox[gg][1] < pr.y) && (pr.y < sbox[gg][3]);
            float mm = ((m > thr[gg]) && inside) ? m : 0.f;
            if (mm > bestv) { bestv = mm; bestg = gg; }   // first max wins
        }
        if (bestv > 0.f) {
            int lab = slab[bestg];
            // focal correction at prior SPL[l]+j, class lab (ref's .at[arange(9)] quirk)
            long pos = (long)b * NPRI + SPLc[l] + j;
            float x  = scores[pos * NCLS + (lab - 1)];
            float e  = expf(-fabsf(x));
            float l1 = log1pf(e);
            float spp = fmaxf(x, 0.f) + l1;
            float spn = fmaxf(-x, 0.f) + l1;
            float p   = (x >= 0.f) ? 1.f / (1.f + e) : e / (1.f + e);
            float corr = 0.25f * (1.f - p) * (1.f - p) * spn - 0.75f * p * p * spp;

            // decode pred box at matched prior, CIoU vs gt
            int pi = tix[bestg * 45 + tid];
            float4 pr = ((const float4*)priors)[SPLc[l] + pi];
            float4 lc = ((const float4*)locs)[b * NPRI + SPLc[l] + pi];
            float cx = lc.x * pr.z / 10.f + pr.x;
            float cy = lc.y * pr.w / 10.f + pr.y;
            float w  = expf(lc.z / 5.f) * pr.z;
            float h  = expf(lc.w / 5.f) * pr.w;
            float qx0 = cx - w * 0.5f, qy0 = cy - h * 0.5f;
            float qx1 = cx + w * 0.5f, qy1 = cy + h * 0.5f;
            float gx0 = sbox[bestg][0], gy0 = sbox[bestg][1];
            float gx1 = sbox[bestg][2], gy1 = sbox[bestg][3];
            float w1 = qx1 - qx0, h1 = qy1 - qy0, w2 = gx1 - gx0, h2 = gy1 - gy0;
            float iw = fmaxf(fminf(qx1, gx1) - fmaxf(qx0, gx0), 0.f);
            float ih = fmaxf(fminf(qy1, gy1) - fmaxf(qy0, gy0), 0.f);
            float inter = iw * ih;
            float iou = inter / (w1 * h1 + w2 * h2 - inter);
            float dcx = (qx0 + qx1) * 0.5f - (gx0 + gx1) * 0.5f;
            float dcy = (qy0 + qy1) * 0.5f - (gy0 + gy1) * 0.5f;
            float rho2 = dcx * dcx + dcy * dcy;
            float ex = fmaxf(qx1, gx1) - fminf(qx0, gx0);
            float ey = fmaxf(qy1, gy1) - fminf(qy0, gy0);
            float cdiag = ex * ex + ey * ey;
            float da = atanf(w2 / h2) - atanf(w1 / h1);
            float v  = 0.4052847345693511f * da * da;     // 4/pi^2
            float alpha = v / (1.f - iou + v);
            float ci = iou - rho2 / cdiag - alpha * v;
            ci = fminf(fmaxf(ci, -1.f), 1.f);

            atomicAdd(&rc, corr);       // LDS atomics, block-local
            atomicAdd(&rl, 1.f - ci);
            atomicAdd(&rn, 1);
        }
    }
    __syncthreads();
    if (tid == 0) {
        imgstats[b * 3 + 0] = rc;
        imgstats[b * 3 + 1] = rl;
        imgstats[b * 3 + 2] = (float)rn;
    }
}

// ------------------------------------------------------------------ kernel 3
__global__ __launch_bounds__(256)
void atss_finalize(const float* __restrict__ partials,
                   const float* __restrict__ imgstats,
                   float* __restrict__ out)
{
    const int tid = threadIdx.x;
    __shared__ float wsum[4];
    float lsum = 0.f;
    for (int i = tid; i < FOCAL_BLOCKS; i += 256) lsum += partials[i];
    #pragma unroll
    for (int off = 32; off > 0; off >>= 1) lsum += __shfl_down(lsum, off);
    if ((tid & 63) == 0) wsum[tid >> 6] = lsum;
    __syncthreads();
    if (tid == 0) {
        float base = 0.75f * (wsum[0] + wsum[1] + wsum[2] + wsum[3]);
        float corr = 0.f, loc = 0.f, cnt = 0.f;
        for (int b = 0; b < NIMG; ++b) {
            corr += imgstats[b * 3 + 0];
            loc  += imgstats[b * 3 + 1];
            cnt  += imgstats[b * 3 + 2];
        }
        float conf = (base + corr) / cnt;            // ref: / n_pos (no clamp)
        float locl = loc / fmaxf(cnt, 1.f);          // ref: clamped denom
        out[0] = conf + locl;
    }
}

extern "C" void kernel_launch(void* const* d_in, const int* in_sizes, int n_in,
                              void* d_out, int out_size, void* d_ws, size_t ws_size,
                              hipStream_t stream)
{
    const float* locs   = (const float*)d_in[0];   // (32, 8525, 4)
    const float* scores = (const float*)d_in[1];   // (32, 8525, 80)
    const float* boxes  = (const float*)d_in[2];   // (32, 16, 4)
    const int*   labels = (const int*)d_in[3];     // (32, 16)
    const float* priors = (const float*)d_in[4];   // (8525, 4)
    float* out = (float*)d_out;

    float* povs     = (float*)d_ws;
    int*   idxs     = (int*)((char*)d_ws + OFF_IDXS);
    float* partials = (float*)((char*)d_ws + OFF_PART);
    float* imgstats = (float*)((char*)d_ws + OFF_IMG);

    atss_main<<<TOTAL_BLOCKS, 256, 0, stream>>>(scores, boxes, priors,
                                                povs, idxs, partials);
    atss_decide<<<NIMG, 256, 0, stream>>>(locs, scores, boxes, labels, priors,
                                          povs, idxs, imgstats);
    atss_finalize<<<1, 256, 0, stream>>>(partials, imgstats, out);
}

// Round 5
// 154.790 us; speedup vs baseline: 3.3012x; 1.2360x over previous
//
#include <hip/hip_runtime.h>
#include <math.h>

#define KGT   16
#define NCAND 9
#define NLVL  5
#define NPRI  8525
#define NCLS  80
#define NIMG  32

#define SCAN_BLOCKS  10                  // 2560 tasks, one THREAD each (5x5 window trick)
#define FOCAL_BLOCKS 2038
#define TOTAL_BLOCKS 2048                // exactly resident at 8 blocks/CU
#define NELEM (NIMG * NPRI * NCLS)       // 21,824,000
#define N4    (NELEM / 4)                // 5,456,000
#define NTASK (NIMG * KGT * NLVL)        // 2560

// ws layout (bytes), every region fully written each call (no init needed):
//   povs     @ 0      : 23040 f32
//   idxs     @ 92160  : 23040 i32
//   partials @ 184320 : 2038 f32 (per-focal-block partial sums)
//   imgstats @ 192512 : 32 x {corr, loc, cnt} f32
#define OFF_IDXS  92160
#define OFF_PART  184320
#define OFF_IMG   192512

__device__ __forceinline__ float focal_elem(float x)
{
    float e  = __expf(-fabsf(x));                 // e^{-|x|}
    float t  = 1.f + e;
    float r  = __builtin_amdgcn_rcpf(t);          // ~1ulp rcp (2% output tolerance)
    float sp = fmaxf(x, 0.f) + __logf(t);         // softplus(x)
    float nm = (x >= 0.f) ? 1.f : e;
    float p  = nm * r;                            // sigmoid(x)
    return p * p * sp;
}

__device__ __forceinline__ float focal4(float4 v)
{
    return focal_elem(v.x) + focal_elem(v.y) + focal_elem(v.z) + focal_elem(v.w);
}

// ------------------------------------------------------------------ kernel 1
__global__ __launch_bounds__(256)
void atss_main(const float* __restrict__ scores,
               const float* __restrict__ boxes,
               const float* __restrict__ priors,
               float* __restrict__ povs,
               int*   __restrict__ idxs,
               float* __restrict__ partials)
{
    const int tid = threadIdx.x;
    const int blk = blockIdx.x;
    __shared__ float wsum[4];

    if (blk < SCAN_BLOCKS) {
        // One thread per task (b,g,l). The priors of level l form a regular
        // f x f grid with spacing 1/f; the 9 nearest centers to any query lie
        // inside the 5x5 window of nearest rows/cols (9th-nearest <= ~1.6/f,
        // outside-window >= 2.5/f), so scan 25 candidates, not 6400.
        const int SPLc[5]  = {0, 6400, 8000, 8400, 8500};
        const int FDIM[5]  = {80, 40, 20, 10, 5};
        const int t = blk * 256 + tid;          // [0, 2560)
        const int b = t / (KGT * NLVL);
        const int r = t % (KGT * NLVL);
        const int g = r / NLVL;
        const int l = r % NLVL;
        const int f    = FDIM[l];
        const int base = SPLc[l];

        float4 bx = ((const float4*)boxes)[b * KGT + g];
        const float gcx = (bx.x + bx.z) * 0.5f;
        const float gcy = (bx.y + bx.w) * 0.5f;

        const float ff = (float)f;
        int ix0 = (int)floorf(gcx * ff); ix0 = min(max(ix0, 0), f - 1);
        int iy0 = (int)floorf(gcy * ff); iy0 = min(max(iy0, 0), f - 1);
        int sx = min(max(ix0 - 2, 0), f - 5);
        int sy = min(max(iy0 - 2, 0), f - 5);

        unsigned long long L[NCAND];
        #pragma unroll
        for (int s = 0; s < NCAND; ++s) L[s] = ~0ull;

        for (int dy = 0; dy < 5; ++dy) {
            for (int dx = 0; dx < 5; ++dx) {
                int idx = (sy + dy) * f + (sx + dx);   // prior index within level
                float2 pc = ((const float2*)priors)[(base + idx) * 2];
                float ddx = gcx - pc.x, ddy = gcy - pc.y;
                float dist = sqrtf(ddx * ddx + ddy * ddy);   // matches ref rounding
                unsigned long long pk =
                    ((unsigned long long)__float_as_uint(dist) << 32) | (unsigned)idx;
                if (pk < L[NCAND - 1]) {               // lexicographic (dist, idx)
                    L[NCAND - 1] = pk;
                    #pragma unroll
                    for (int s = NCAND - 1; s >= 1; --s) {
                        if (L[s] < L[s - 1]) {
                            unsigned long long tw = L[s]; L[s] = L[s - 1]; L[s - 1] = tw;
                        } else break;
                    }
                }
            }
        }
        // top-9 in ascending (dist, idx) order == lax.top_k order; emit IoUs
        #pragma unroll
        for (int s = 0; s < NCAND; ++s) {
            int idx = (int)(unsigned)(L[s] & 0xffffffffull);
            float4 pr = ((const float4*)priors)[base + idx];
            float px0 = pr.x - pr.z * 0.5f, py0 = pr.y - pr.w * 0.5f;
            float px1 = pr.x + pr.z * 0.5f, py1 = pr.y + pr.w * 0.5f;
            float iw = fmaxf(fminf(bx.z, px1) - fmaxf(bx.x, px0), 0.f);
            float ih = fmaxf(fminf(bx.w, py1) - fmaxf(bx.y, py0), 0.f);
            float inter = iw * ih;
            float areaA = (bx.z - bx.x) * (bx.w - bx.y);
            float areaP = (px1 - px0) * (py1 - py0);
            povs[t * NCAND + s] = inter / (areaA + areaP - inter);
            idxs[t * NCAND + s] = idx;
        }
        return;
    }

    // focal base: sum p^2 * softplus(x) over every logit, 4 loads in flight
    const float4* s4 = (const float4*)scores;
    const int S = FOCAL_BLOCKS * 256;
    int gid = (blk - SCAN_BLOCKS) * 256 + tid;
    float lsum = 0.f;
    for (int bse = gid; bse < N4; bse += 4 * S) {
        int i1 = bse + S, i2 = bse + 2 * S, i3 = bse + 3 * S;
        float4 v0 = s4[bse];
        float4 v1 = s4[min(i1, N4 - 1)];
        float4 v2 = s4[min(i2, N4 - 1)];
        float4 v3 = s4[min(i3, N4 - 1)];
        float t0 = focal4(v0);
        float t1 = focal4(v1);
        float t2 = focal4(v2);
        float t3 = focal4(v3);
        lsum += t0;
        lsum += (i1 < N4) ? t1 : 0.f;
        lsum += (i2 < N4) ? t2 : 0.f;
        lsum += (i3 < N4) ? t3 : 0.f;
    }
    #pragma unroll
    for (int off = 32; off > 0; off >>= 1) lsum += __shfl_down(lsum, off);
    if ((tid & 63) == 0) wsum[tid >> 6] = lsum;
    __syncthreads();
    if (tid == 0)
        partials[blk - SCAN_BLOCKS] = wsum[0] + wsum[1] + wsum[2] + wsum[3];
}

// ------------------------------------------------------------------ kernel 2
// one block per image: threshold, argmax-over-GT, focal correction + CIoU
__global__ __launch_bounds__(256)
void atss_decide(const float* __restrict__ locs,
                 const float* __restrict__ scores,
                 const float* __restrict__ boxes,
                 const int*   __restrict__ labels,
                 const float* __restrict__ priors,
                 const float* __restrict__ povs,
                 const int*   __restrict__ idxs,
                 float* __restrict__ imgstats)
{
    const int tid = threadIdx.x;
    const int b = blockIdx.x;
    const int SPLc[6] = {0, 6400, 8000, 8400, 8500, 8525};

    __shared__ float pov[KGT * 45];
    __shared__ int   tix[KGT * 45];
    __shared__ float sbox[KGT][4];
    __shared__ int   slab[KGT];
    __shared__ float thr[KGT];
    __shared__ float rc, rl;
    __shared__ int   rn;

    if (tid == 0) { rc = 0.f; rl = 0.f; rn = 0; }
    for (int e = tid; e < KGT * 45; e += 256) {
        pov[e] = povs[b * (KGT * 45) + e];
        tix[e] = idxs[b * (KGT * 45) + e];
    }
    if (tid < KGT) {
        float4 bxv = ((const float4*)boxes)[b * KGT + tid];
        sbox[tid][0] = bxv.x; sbox[tid][1] = bxv.y;
        sbox[tid][2] = bxv.z; sbox[tid][3] = bxv.w;
        slab[tid] = labels[b * KGT + tid];
    }
    __syncthreads();

    if (tid < KGT) {   // mean + std(ddof=1) over the 45 candidate IoUs
        float s = 0.f;
        for (int q = 0; q < 45; ++q) s += pov[tid * 45 + q];
        float mean = s / 45.f;
        float ss = 0.f;
        for (int q = 0; q < 45; ++q) { float d = pov[tid * 45 + q] - mean; ss += d * d; }
        thr[tid] = mean + sqrtf(ss / 44.f);
    }
    __syncthreads();

    if (tid < NLVL * NCAND) {
        int l = tid / NCAND, j = tid % NCAND;
        float bestv = -1.f; int bestg = 0;
        #pragma unroll
        for (int gg = 0; gg < KGT; ++gg) {
            float m = pov[gg * 45 + tid];
            int pi = tix[gg * 45 + tid];
            float4 pr = ((const float4*)priors)[SPLc[l] + pi];
            bool inside = (sbox[gg][0] < pr.x) && (pr.x < sbox[gg][2]) &&
                          (sbox[gg][1] < pr.y) && (pr.y < sbox[gg][3]);
            float mm = ((m > thr[gg]) && inside) ? m : 0.f;
            if (mm > bestv) { bestv = mm; bestg = gg; }   // first max wins
        }
        if (bestv > 0.f) {
            int lab = slab[bestg];
            // focal correction at prior SPL[l]+j, class lab (ref's .at[arange(9)] quirk)
            long pos = (long)b * NPRI + SPLc[l] + j;
            float x  = scores[pos * NCLS + (lab - 1)];
            float e  = expf(-fabsf(x));
            float l1 = log1pf(e);
            float spp = fmaxf(x, 0.f) + l1;
            float spn = fmaxf(-x, 0.f) + l1;
            float p   = (x >= 0.f) ? 1.f / (1.f + e) : e / (1.f + e);
            float corr = 0.25f * (1.f - p) * (1.f - p) * spn - 0.75f * p * p * spp;

            // decode pred box at matched prior, CIoU vs gt
            int pi = tix[bestg * 45 + tid];
            float4 pr = ((const float4*)priors)[SPLc[l] + pi];
            float4 lc = ((const float4*)locs)[b * NPRI + SPLc[l] + pi];
            float cx = lc.x * pr.z / 10.f + pr.x;
            float cy = lc.y * pr.w / 10.f + pr.y;
            float w  = expf(lc.z / 5.f) * pr.z;
            float h  = expf(lc.w / 5.f) * pr.w;
            float qx0 = cx - w * 0.5f, qy0 = cy - h * 0.5f;
            float qx1 = cx + w * 0.5f, qy1 = cy + h * 0.5f;
            float gx0 = sbox[bestg][0], gy0 = sbox[bestg][1];
            float gx1 = sbox[bestg][2], gy1 = sbox[bestg][3];
            float w1 = qx1 - qx0, h1 = qy1 - qy0, w2 = gx1 - gx0, h2 = gy1 - gy0;
            float iw = fmaxf(fminf(qx1, gx1) - fmaxf(qx0, gx0), 0.f);
            float ih = fmaxf(fminf(qy1, gy1) - fmaxf(qy0, gy0), 0.f);
            float inter = iw * ih;
            float iou = inter / (w1 * h1 + w2 * h2 - inter);
            float dcx = (qx0 + qx1) * 0.5f - (gx0 + gx1) * 0.5f;
            float dcy = (qy0 + qy1) * 0.5f - (gy0 + gy1) * 0.5f;
            float rho2 = dcx * dcx + dcy * dcy;
            float ex = fmaxf(qx1, gx1) - fminf(qx0, gx0);
            float ey = fmaxf(qy1, gy1) - fminf(qy0, gy0);
            float cdiag = ex * ex + ey * ey;
            float da = atanf(w2 / h2) - atanf(w1 / h1);
            float v  = 0.4052847345693511f * da * da;     // 4/pi^2
            float alpha = v / (1.f - iou + v);
            float ci = iou - rho2 / cdiag - alpha * v;
            ci = fminf(fmaxf(ci, -1.f), 1.f);

            atomicAdd(&rc, corr);       // LDS atomics, block-local
            atomicAdd(&rl, 1.f - ci);
            atomicAdd(&rn, 1);
        }
    }
    __syncthreads();
    if (tid == 0) {
        imgstats[b * 3 + 0] = rc;
        imgstats[b * 3 + 1] = rl;
        imgstats[b * 3 + 2] = (float)rn;
    }
}

// ------------------------------------------------------------------ kernel 3
__global__ __launch_bounds__(256)
void atss_finalize(const float* __restrict__ partials,
                   const float* __restrict__ imgstats,
                   float* __restrict__ out)
{
    const int tid = threadIdx.x;
    __shared__ float wsum[4];
    float lsum = 0.f;
    for (int i = tid; i < FOCAL_BLOCKS; i += 256) lsum += partials[i];
    #pragma unroll
    for (int off = 32; off > 0; off >>= 1) lsum += __shfl_down(lsum, off);
    if ((tid & 63) == 0) wsum[tid >> 6] = lsum;
    __syncthreads();
    if (tid == 0) {
        float base = 0.75f * (wsum[0] + wsum[1] + wsum[2] + wsum[3]);
        float corr = 0.f, loc = 0.f, cnt = 0.f;
        for (int b = 0; b < NIMG; ++b) {
            corr += imgstats[b * 3 + 0];
            loc  += imgstats[b * 3 + 1];
            cnt  += imgstats[b * 3 + 2];
        }
        float conf = (base + corr) / cnt;            // ref: / n_pos (no clamp)
        float locl = loc / fmaxf(cnt, 1.f);          // ref: clamped denom
        out[0] = conf + locl;
    }
}

extern "C" void kernel_launch(void* const* d_in, const int* in_sizes, int n_in,
                              void* d_out, int out_size, void* d_ws, size_t ws_size,
                              hipStream_t stream)
{
    const float* locs   = (const float*)d_in[0];   // (32, 8525, 4)
    const float* scores = (const float*)d_in[1];   // (32, 8525, 80)
    const float* boxes  = (const float*)d_in[2];   // (32, 16, 4)
    const int*   labels = (const int*)d_in[3];     // (32, 16)
    const float* priors = (const float*)d_in[4];   // (8525, 4)
    float* out = (float*)d_out;

    float* povs     = (float*)d_ws;
    int*   idxs     = (int*)((char*)d_ws + OFF_IDXS);
    float* partials = (float*)((char*)d_ws + OFF_PART);
    float* imgstats = (float*)((char*)d_ws + OFF_IMG);

    atss_main<<<TOTAL_BLOCKS, 256, 0, stream>>>(scores, boxes, priors,
                                                povs, idxs, partials);
    atss_decide<<<NIMG, 256, 0, stream>>>(locs, scores, boxes, labels, priors,
                                          povs, idxs, imgstats);
    atss_finalize<<<1, 256, 0, stream>>>(partials, imgstats, out);
}